// Round 5
// baseline (416.490 us; speedup 1.0000x reference)
//
#include <hip/hip_runtime.h>
#include <hip/hip_bf16.h>

// Problem constants: B=4, C=512, H=W=64 -> N=4096, CK=64
#define NB 4
#define CC 512
#define NN 4096
#define CKK 64
#define NT 32   // NN/128 j-tiles

typedef _Float16 f16x4 __attribute__((ext_vector_type(4)));
typedef _Float16 f16x8 __attribute__((ext_vector_type(8)));
typedef float    f32x4 __attribute__((ext_vector_type(4)));

// ---------------------------------------------------------------------------
// async global->LDS, 16 B per lane. LDS dest is wave-uniform base + lane*16.
// ---------------------------------------------------------------------------
__device__ __forceinline__ void g2l16(const _Float16* g, _Float16* l) {
    __builtin_amdgcn_global_load_lds(
        (const __attribute__((address_space(1))) void*)g,
        (__attribute__((address_space(3))) void*)l, 16, 0, 0);
}

// Stage a 128-row x 32-col f16 tile (row stride ldg) into LDS [128][32],
// 256 threads (4 waves). Linear layout (used by proj).
__device__ __forceinline__ void stage_tile(const _Float16* __restrict__ g, int ldg,
                                           _Float16* lds, int lane, int wave) {
    #pragma unroll
    for (int r = 0; r < 2; r++) {
        int q = r * 4 + wave;
        int row = q * 16 + (lane >> 2);
        int col = (lane & 3) * 8;
        g2l16(g + (size_t)row * ldg + col, lds + q * 512 + lane * 8);
    }
}

// Stage a 128x32 f16 tile with 512 threads, ONE g2l16 per thread.
// LDS dest linear (required by global_load_lds); the GLOBAL source chunk is
// pre-permuted by (row>>1)&3 -> stored layout is XOR-swizzled; rd_swz reads.
__device__ __forceinline__ void stage_swz(const _Float16* __restrict__ g, int ldg,
                                          _Float16* lds, int tid) {
    int row = tid >> 2;
    int scq = (tid & 3) ^ ((row >> 1) & 3);
    g2l16(g + (size_t)row * ldg + scq * 8, lds + tid * 8);
}

__device__ __forceinline__ f16x8 rd_swz(const _Float16* lds, int row, int quad) {
    int q = quad ^ ((row >> 1) & 3);
    return *(const f16x8*)(lds + row * 32 + q * 8);
}

// pack two floats to packed-f16 u32 (low = a)
__device__ __forceinline__ uint32_t pkh(float a, float b) {
    union { _Float16 h[2]; uint32_t u; } v;
    v.h[0] = (_Float16)a; v.h[1] = (_Float16)b;
    return v.u;
}

// ---------------------------------------------------------------------------
// K0 "prep": blocks 0..2047 transpose x (fp32 [B][C][N]) -> xT (f16 [B][N][C]);
// blocks 2048..2687 pack Wf/Wg/Wh -> Wall[640][512] f16 + Ball[640] fp32.
// ---------------------------------------------------------------------------
__launch_bounds__(256)
__global__ void prep(const float* __restrict__ x, _Float16* __restrict__ xT,
                     const float* __restrict__ Wf, const float* __restrict__ bf_,
                     const float* __restrict__ Wg, const float* __restrict__ bg_,
                     const float* __restrict__ Wh, const float* __restrict__ bh_,
                     _Float16* __restrict__ Wall, float* __restrict__ Ball) {
    const int N = NN, C = CC;
    int bid = blockIdx.x;
    int t = threadIdx.x;
    if (bid < 2048) {
        int n0 = (bid & 63) << 6;
        int c0 = ((bid >> 6) & 7) << 6;
        int b  = bid >> 9;
        __shared__ float T[64][65];
        const float* xb = x + (size_t)b * C * N;
        #pragma unroll
        for (int r = 0; r < 4; r++) {
            int c = (t >> 4) + 16 * r;
            int n4 = (t & 15) * 4;
            float4 v = *(const float4*)(xb + (size_t)(c0 + c) * N + n0 + n4);
            T[n4 + 0][c] = v.x; T[n4 + 1][c] = v.y; T[n4 + 2][c] = v.z; T[n4 + 3][c] = v.w;
        }
        __syncthreads();
        int n = t >> 2, cb = (t & 3) * 16;
        f16x8 h0, h1;
        #pragma unroll
        for (int i = 0; i < 8; i++) { h0[i] = (_Float16)T[n][cb + i]; h1[i] = (_Float16)T[n][cb + 8 + i]; }
        _Float16* dst = xT + (size_t)b * N * C + (size_t)(n0 + n) * C + c0 + cb;
        *(f16x8*)dst = h0;
        *(f16x8*)(dst + 8) = h1;
    } else {
        int o = bid - 2048;  // 0..639
        const float* src;
        if (o < 64)       src = Wf + (size_t)o * C;
        else if (o < 128) src = Wg + (size_t)(o - 64) * C;
        else              src = Wh + (size_t)(o - 128) * C;
        Wall[(size_t)o * C + t]       = (_Float16)src[t];
        Wall[(size_t)o * C + 256 + t] = (_Float16)src[256 + t];
        if (t == 0)
            Ball[o] = (o < 64) ? bf_[o] : (o < 128 ? bg_[o - 64] : bh_[o - 128]);
    }
}

// ---------------------------------------------------------------------------
// K1: projections, NT MFMA GEMM. Y[o][n] = sum_c Wall[o][c]*xT[n][c] + Ball[o]
// ---------------------------------------------------------------------------
__launch_bounds__(256)
__global__ void proj_mfma(const _Float16* __restrict__ xT, const _Float16* __restrict__ Wall,
                          const float* __restrict__ Ball,
                          _Float16* __restrict__ Ft, _Float16* __restrict__ Gt,
                          _Float16* __restrict__ Hx) {
    const int N = NN, C = CC;
    int n0 = blockIdx.x * 128;
    int o0 = blockIdx.y * 128;
    int b  = blockIdx.z;
    const _Float16* Arow = Wall + (size_t)o0 * C;
    const _Float16* Brow = xT + (size_t)b * N * C + (size_t)n0 * C;
    __shared__ _Float16 As[128 * 32];
    __shared__ _Float16 Bs[128 * 32];
    int tid = threadIdx.x, lane = tid & 63, wave = tid >> 6;
    int wm = wave & 1, wn = wave >> 1, lrow = lane & 15, quad = lane >> 4;
    f32x4 acc[4][4] = {};
    for (int kc = 0; kc < C; kc += 32) {
        __syncthreads();
        stage_tile(Arow + kc, C, As, lane, wave);
        stage_tile(Brow + kc, C, Bs, lane, wave);
        __syncthreads();
        f16x8 af[4], bf[4];
        #pragma unroll
        for (int mi = 0; mi < 4; mi++)
            af[mi] = *(const f16x8*)(As + (wm * 64 + mi * 16 + lrow) * 32 + quad * 8);
        #pragma unroll
        for (int ni = 0; ni < 4; ni++)
            bf[ni] = *(const f16x8*)(Bs + (wn * 64 + ni * 16 + lrow) * 32 + quad * 8);
        #pragma unroll
        for (int mi = 0; mi < 4; mi++)
            #pragma unroll
            for (int ni = 0; ni < 4; ni++)
                acc[mi][ni] = __builtin_amdgcn_mfma_f32_16x16x32_f16(af[mi], bf[ni], acc[mi][ni], 0, 0, 0);
    }
    float bias_r[4][4];
    #pragma unroll
    for (int mi = 0; mi < 4; mi++)
        #pragma unroll
        for (int r = 0; r < 4; r++)
            bias_r[mi][r] = Ball[o0 + wm * 64 + mi * 16 + quad * 4 + r];
    _Float16* Ftb = Ft + (size_t)b * NN * CKK;
    _Float16* Gtb = Gt + (size_t)b * NN * CKK;
    _Float16* Hxb = Hx + (size_t)b * CC * N;
    #pragma unroll
    for (int mi = 0; mi < 4; mi++)
        #pragma unroll
        for (int ni = 0; ni < 4; ni++) {
            int o = o0 + wm * 64 + mi * 16 + quad * 4;
            int n = n0 + wn * 64 + ni * 16 + lrow;
            f16x4 v;
            #pragma unroll
            for (int r = 0; r < 4; r++) v[r] = (_Float16)(acc[mi][ni][r] + bias_r[mi][r]);
            if (o < 64)       *(f16x4*)(Ftb + (size_t)n * CKK + o) = v;
            else if (o < 128) *(f16x4*)(Gtb + (size_t)n * CKK + (o - 64)) = v;
            else {
                #pragma unroll
                for (int r = 0; r < 4; r++)
                    Hxb[(size_t)(o - 128 + r) * N + n] = v[r];
            }
        }
}

// ---------------------------------------------------------------------------
// K2: fused flash attention, lane-local softmax (swapped-operand S^T).
// Block: 128 i x 128 c, 512 threads (8 waves), grid 512 flat (XCD-swizzled).
// Wave w owns i-rows [16w,16w+16) for BOTH S and PV.
//   S^T = mfma(Gt_frag, Ft_frag): D[row=j][col=i] -> column i = lane&15 is
//   thread-local => row max / row sum = in-thread reduce + shfl_xor(16,32).
//   m,l live in REGISTERS. P' packed to f16 pairs in-register; PV B-frags
//   assembled via 8 ds_bpermute per kk (index algebra verified). No Pst, no
//   Mred, no BsG: Gt frags load direct from global (coalesced, L2-resident).
// LDS: only Hx tile, dbuf 2 x 4 x [128][32] swizzled chunks = 64 KB
//   -> 2 blocks/CU. Staged one full j-tile ahead.
// Barriers: 2/jt. alpha = vmcnt(4)+barrier (all waves' Ah(jt) landed; the 4
//   outstanding = Ah(jt+1)); beta = plain barrier (PV readers done before the
//   next iteration's overwrite). No vmcnt(0) drains in the loop.
// ---------------------------------------------------------------------------
#define SM_TOTAL 65536

__launch_bounds__(512, 4)
__global__ void attn_fused(const _Float16* __restrict__ Ft, const _Float16* __restrict__ Gt,
                           const _Float16* __restrict__ Hx, const float* __restrict__ x,
                           const float* __restrict__ gamma, float* __restrict__ out) {
    const int N = NN;
    extern __shared__ char smem[];
    _Float16* AhL = (_Float16*)smem;   // 2 bufs x 4 chunks x [128][32] f16

    // XCD-aware decomposition: hw block h -> logical l so each XCD gets
    // contiguous 64 logical blocks = all 32 i-tiles of 2 (c,b) slices.
    int h = blockIdx.x;
    int l = (h & 7) * 64 + (h >> 3);
    int bx = l & 31;
    int rem = l >> 5;
    int by = rem & 3;
    int b  = rem >> 2;
    const int i0 = bx * 128;
    const int c0 = by * 128;

    const int tid = threadIdx.x;
    const int lane = tid & 63, w = tid >> 6;
    const int lrow = lane & 15, quad = lane >> 4;

    const _Float16* Ftb = Ft + ((size_t)b * N + i0 + w * 16) * CKK;
    const _Float16* Gtb = Gt + (size_t)b * N * CKK;
    const _Float16* Hxb = Hx + ((size_t)b * CC + c0) * N;

    // prologue: stage Ah(0) -> buf0; Ft B-frags direct to registers
    #pragma unroll
    for (int kk = 0; kk < 4; kk++)
        stage_swz(Hxb + kk * 32, N, AhL + kk * 4096, tid);

    f16x8 ftf[2];
    #pragma unroll
    for (int ks = 0; ks < 2; ks++)
        ftf[ks] = *(const f16x8*)(Ftb + (size_t)lrow * CKK + ks * 32 + quad * 8);

    f32x4 acc[8] = {};
    float m_run = -1e30f, l_run = 0.0f;
    const int src0 = (quad & 1) * 32 + lrow;  // lane of source quad (quad&1)*2
    const int src1 = src0 + 16;

    #pragma unroll 1
    for (int jt = 0; jt < NT; jt++) {
        const int p = jt & 1;
        // ---- stage Ah(jt+1) -> buf p^1 (read buf was PV(jt-1)'s, fenced by beta) ----
        {
            const int jn = (jt + 1) & (NT - 1);
            const _Float16* Hn = Hxb + (size_t)jn * 128;
            _Float16* dst = AhL + (p ^ 1) * 16384;
            #pragma unroll
            for (int kk = 0; kk < 4; kk++)
                stage_swz(Hn + kk * 32, N, dst + kk * 4096, tid);
        }
        // ---- S^T = Gt_frag . Ft_frag : sacc[jf] reg r = S[j=jf*16+quad*4+r][i=lrow] ----
        f32x4 sacc[8] = {};
        const _Float16* Gr = Gtb + (size_t)jt * 128 * CKK;
        #pragma unroll
        for (int ks = 0; ks < 2; ks++)
            #pragma unroll
            for (int jf = 0; jf < 8; jf++) {
                f16x8 ga = *(const f16x8*)(Gr + (size_t)(jf * 16 + lrow) * CKK + ks * 32 + quad * 8);
                sacc[jf] = __builtin_amdgcn_mfma_f32_16x16x32_f16(ga, ftf[ks], sacc[jf], 0, 0, 0);
            }
        // ---- lane-local online softmax (thread owns column i = lrow) ----
        float mt;
        {
            float m0 = fmaxf(fmaxf(sacc[0][0], sacc[0][1]), fmaxf(sacc[0][2], sacc[0][3]));
            #pragma unroll
            for (int jf = 1; jf < 8; jf++) {
                float mv = fmaxf(fmaxf(sacc[jf][0], sacc[jf][1]), fmaxf(sacc[jf][2], sacc[jf][3]));
                m0 = fmaxf(m0, mv);
            }
            m0 = fmaxf(m0, __shfl_xor(m0, 16));
            mt = fmaxf(m0, __shfl_xor(m0, 32));
        }
        const float mn = fmaxf(m_run, mt);
        const float sc = __expf(m_run - mn);   // first tile: exp(-huge) = 0
        m_run = mn;
        // rescale O accumulator (per-thread scalar, all regs same column i)
        #pragma unroll
        for (int cf = 0; cf < 8; cf++)
            #pragma unroll
            for (int r = 0; r < 4; r++)
                acc[cf][r] *= sc;
        // P' = exp(s - m) packed to f16 pairs in-register; l-sum in f32
        uint32_t p01[8], p23[8];
        float ls = 0.0f;
        #pragma unroll
        for (int jf = 0; jf < 8; jf++) {
            float e0 = __expf(sacc[jf][0] - mn);
            float e1 = __expf(sacc[jf][1] - mn);
            float e2 = __expf(sacc[jf][2] - mn);
            float e3 = __expf(sacc[jf][3] - mn);
            ls += (e0 + e1) + (e2 + e3);
            p01[jf] = pkh(e0, e1);
            p23[jf] = pkh(e2, e3);
        }
        ls += __shfl_xor(ls, 16);
        ls += __shfl_xor(ls, 32);
        l_run = l_run * sc + ls;
        // ---- alpha: all waves' Ah(jt) landed (own 4 oldest retired; 4 newest = Ah(jt+1)) ----
        asm volatile("s_waitcnt vmcnt(4)\n\ts_barrier" ::: "memory");
        // ---- PV: O[c][i] += Hx[c][j] * P'[i][j], 4 k-chunks of 32 ----
        const _Float16* Ab = AhL + p * 16384;
        #pragma unroll
        for (int kk = 0; kk < 4; kk++) {
            // assemble B-frag: b[t] = P'[i=lrow][j = kk*32 + quad*8 + t]
            uint32_t a0 = __shfl(p01[2 * kk], src0);
            uint32_t a1 = __shfl(p23[2 * kk], src0);
            uint32_t a2 = __shfl(p01[2 * kk], src1);
            uint32_t a3 = __shfl(p23[2 * kk], src1);
            uint32_t b0 = __shfl(p01[2 * kk + 1], src0);
            uint32_t b1 = __shfl(p23[2 * kk + 1], src0);
            uint32_t b2 = __shfl(p01[2 * kk + 1], src1);
            uint32_t b3 = __shfl(p23[2 * kk + 1], src1);
            union { uint32_t u[4]; f16x8 v; } bb;
            bool hi = (quad & 2) != 0;    // frag 2kk+1 for quads 2,3
            bb.u[0] = hi ? b0 : a0;
            bb.u[1] = hi ? b1 : a1;
            bb.u[2] = hi ? b2 : a2;
            bb.u[3] = hi ? b3 : a3;
            #pragma unroll
            for (int cf = 0; cf < 8; cf++) {
                f16x8 av = rd_swz(Ab + kk * 4096, cf * 16 + lrow, quad);
                acc[cf] = __builtin_amdgcn_mfma_f32_16x16x32_f16(av, bb.v, acc[cf], 0, 0, 0);
            }
        }
        // ---- beta: PV readers done before next iteration overwrites buf p^1's pair ----
        asm volatile("s_barrier" ::: "memory");
    }

    // ---- epilogue: out = gamma * (O / l) + x ----
    const float gv = gamma[0];
    const float li = 1.0f / l_run;
    const float* xb = x + (size_t)b * CC * N;
    float* ob = out + (size_t)b * CC * N;
    const int iG = i0 + w * 16 + lrow;
    #pragma unroll
    for (int cf = 0; cf < 8; cf++)
        #pragma unroll
        for (int r = 0; r < 4; r++) {
            int c = c0 + cf * 16 + quad * 4 + r;
            ob[(size_t)c * N + iG] = gv * (acc[cf][r] * li) + xb[(size_t)c * N + iG];
        }
}

extern "C" void kernel_launch(void* const* d_in, const int* in_sizes, int n_in,
                              void* d_out, int out_size, void* d_ws, size_t ws_size,
                              hipStream_t stream) {
    const float* x     = (const float*)d_in[0];
    const float* Wf    = (const float*)d_in[1];
    const float* bf    = (const float*)d_in[2];
    const float* Wg    = (const float*)d_in[3];
    const float* bg    = (const float*)d_in[4];
    const float* Wh    = (const float*)d_in[5];
    const float* bh    = (const float*)d_in[6];
    const float* gamma = (const float*)d_in[7];
    float* out = (float*)d_out;

    // Workspace layout (bytes):
    //   Wall [640][512] f16    @ 0        (640 KiB)
    //   Ball [640]      fp32   @ 768 KiB
    //   Ft   [B][N][64] f16    @ 1 MiB    (2 MiB)
    //   Gt   [B][N][64] f16    @ 3 MiB    (2 MiB)
    //   Hx   [B][C][N]  f16    @ 5 MiB    (16 MiB)
    //   xT   [B][N][C]  f16    @ 21 MiB   (17 MiB)
    char* wsb = (char*)d_ws;
    _Float16* Wall = (_Float16*)wsb;
    float*    Ball = (float*)(wsb + ((size_t)768 << 10));
    _Float16* Ft = (_Float16*)(wsb + ((size_t)1 << 20));
    _Float16* Gt = (_Float16*)(wsb + ((size_t)3 << 20));
    _Float16* Hx = (_Float16*)(wsb + ((size_t)5 << 20));
    _Float16* xT = (_Float16*)(wsb + ((size_t)21 << 20));

    static const bool attn_attr_once = [] {
        hipFuncSetAttribute((const void*)attn_fused,
                            hipFuncAttributeMaxDynamicSharedMemorySize, SM_TOTAL);
        return true;
    }();
    (void)attn_attr_once;

    prep<<<dim3(2048 + 640), dim3(256), 0, stream>>>(
        x, xT, Wf, bf, Wg, bg, Wh, bh, Wall, Ball);
    proj_mfma<<<dim3(NN / 128, 5, NB), dim3(256), 0, stream>>>(xT, Wall, Ball, Ft, Gt, Hx);
    attn_fused<<<dim3(512), dim3(512), SM_TOTAL, stream>>>(
        Ft, Gt, Hx, x, gamma, out);
}

// Round 6
// 254.991 us; speedup vs baseline: 1.6334x; 1.6334x over previous
//
#include <hip/hip_runtime.h>
#include <hip/hip_bf16.h>

// Problem constants: B=4, C=512, H=W=64 -> N=4096, CK=64
#define NB 4
#define CC 512
#define NN 4096
#define CKK 64
#define NT 32   // NN/128 j-tiles

typedef _Float16 f16x4 __attribute__((ext_vector_type(4)));
typedef _Float16 f16x8 __attribute__((ext_vector_type(8)));
typedef float    f32x4 __attribute__((ext_vector_type(4)));

// ---------------------------------------------------------------------------
// async global->LDS, 16 B per lane. LDS dest is wave-uniform base + lane*16.
// ---------------------------------------------------------------------------
__device__ __forceinline__ void g2l16(const _Float16* g, _Float16* l) {
    __builtin_amdgcn_global_load_lds(
        (const __attribute__((address_space(1))) void*)g,
        (__attribute__((address_space(3))) void*)l, 16, 0, 0);
}

// Stage a 128-row x 32-col f16 tile (row stride ldg) into LDS [128][32],
// 256 threads (4 waves). Linear layout (used by proj).
__device__ __forceinline__ void stage_tile(const _Float16* __restrict__ g, int ldg,
                                           _Float16* lds, int lane, int wave) {
    #pragma unroll
    for (int r = 0; r < 2; r++) {
        int q = r * 4 + wave;
        int row = q * 16 + (lane >> 2);
        int col = (lane & 3) * 8;
        g2l16(g + (size_t)row * ldg + col, lds + q * 512 + lane * 8);
    }
}

// Stage a 128x32 f16 tile with 512 threads, ONE g2l16 per thread.
// LDS dest linear (required by global_load_lds); the GLOBAL source chunk is
// pre-permuted by (row>>1)&3 -> stored layout is XOR-swizzled; rd_swz reads.
__device__ __forceinline__ void stage_swz(const _Float16* __restrict__ g, int ldg,
                                          _Float16* lds, int tid) {
    int row = tid >> 2;
    int scq = (tid & 3) ^ ((row >> 1) & 3);
    g2l16(g + (size_t)row * ldg + scq * 8, lds + tid * 8);
}

__device__ __forceinline__ f16x8 rd_swz(const _Float16* lds, int row, int quad) {
    int q = quad ^ ((row >> 1) & 3);
    return *(const f16x8*)(lds + row * 32 + q * 8);
}

// ---------------------------------------------------------------------------
// K0 "prep": blocks 0..2047 transpose x (fp32 [B][C][N]) -> xT (f16 [B][N][C]);
// blocks 2048..2687 pack Wf/Wg/Wh -> Wall[640][512] f16 + Ball[640] fp32.
// ---------------------------------------------------------------------------
__launch_bounds__(256)
__global__ void prep(const float* __restrict__ x, _Float16* __restrict__ xT,
                     const float* __restrict__ Wf, const float* __restrict__ bf_,
                     const float* __restrict__ Wg, const float* __restrict__ bg_,
                     const float* __restrict__ Wh, const float* __restrict__ bh_,
                     _Float16* __restrict__ Wall, float* __restrict__ Ball) {
    const int N = NN, C = CC;
    int bid = blockIdx.x;
    int t = threadIdx.x;
    if (bid < 2048) {
        int n0 = (bid & 63) << 6;
        int c0 = ((bid >> 6) & 7) << 6;
        int b  = bid >> 9;
        __shared__ float T[64][65];
        const float* xb = x + (size_t)b * C * N;
        #pragma unroll
        for (int r = 0; r < 4; r++) {
            int c = (t >> 4) + 16 * r;
            int n4 = (t & 15) * 4;
            float4 v = *(const float4*)(xb + (size_t)(c0 + c) * N + n0 + n4);
            T[n4 + 0][c] = v.x; T[n4 + 1][c] = v.y; T[n4 + 2][c] = v.z; T[n4 + 3][c] = v.w;
        }
        __syncthreads();
        int n = t >> 2, cb = (t & 3) * 16;
        f16x8 h0, h1;
        #pragma unroll
        for (int i = 0; i < 8; i++) { h0[i] = (_Float16)T[n][cb + i]; h1[i] = (_Float16)T[n][cb + 8 + i]; }
        _Float16* dst = xT + (size_t)b * N * C + (size_t)(n0 + n) * C + c0 + cb;
        *(f16x8*)dst = h0;
        *(f16x8*)(dst + 8) = h1;
    } else {
        int o = bid - 2048;  // 0..639
        const float* src;
        if (o < 64)       src = Wf + (size_t)o * C;
        else if (o < 128) src = Wg + (size_t)(o - 64) * C;
        else              src = Wh + (size_t)(o - 128) * C;
        Wall[(size_t)o * C + t]       = (_Float16)src[t];
        Wall[(size_t)o * C + 256 + t] = (_Float16)src[256 + t];
        if (t == 0)
            Ball[o] = (o < 64) ? bf_[o] : (o < 128 ? bg_[o - 64] : bh_[o - 128]);
    }
}

// ---------------------------------------------------------------------------
// K1: projections, NT MFMA GEMM. Y[o][n] = sum_c Wall[o][c]*xT[n][c] + Ball[o]
// ---------------------------------------------------------------------------
__launch_bounds__(256)
__global__ void proj_mfma(const _Float16* __restrict__ xT, const _Float16* __restrict__ Wall,
                          const float* __restrict__ Ball,
                          _Float16* __restrict__ Ft, _Float16* __restrict__ Gt,
                          _Float16* __restrict__ Hx) {
    const int N = NN, C = CC;
    int n0 = blockIdx.x * 128;
    int o0 = blockIdx.y * 128;
    int b  = blockIdx.z;
    const _Float16* Arow = Wall + (size_t)o0 * C;
    const _Float16* Brow = xT + (size_t)b * N * C + (size_t)n0 * C;
    __shared__ _Float16 As[128 * 32];
    __shared__ _Float16 Bs[128 * 32];
    int tid = threadIdx.x, lane = tid & 63, wave = tid >> 6;
    int wm = wave & 1, wn = wave >> 1, lrow = lane & 15, quad = lane >> 4;
    f32x4 acc[4][4] = {};
    for (int kc = 0; kc < C; kc += 32) {
        __syncthreads();
        stage_tile(Arow + kc, C, As, lane, wave);
        stage_tile(Brow + kc, C, Bs, lane, wave);
        __syncthreads();
        f16x8 af[4], bf[4];
        #pragma unroll
        for (int mi = 0; mi < 4; mi++)
            af[mi] = *(const f16x8*)(As + (wm * 64 + mi * 16 + lrow) * 32 + quad * 8);
        #pragma unroll
        for (int ni = 0; ni < 4; ni++)
            bf[ni] = *(const f16x8*)(Bs + (wn * 64 + ni * 16 + lrow) * 32 + quad * 8);
        #pragma unroll
        for (int mi = 0; mi < 4; mi++)
            #pragma unroll
            for (int ni = 0; ni < 4; ni++)
                acc[mi][ni] = __builtin_amdgcn_mfma_f32_16x16x32_f16(af[mi], bf[ni], acc[mi][ni], 0, 0, 0);
    }
    float bias_r[4][4];
    #pragma unroll
    for (int mi = 0; mi < 4; mi++)
        #pragma unroll
        for (int r = 0; r < 4; r++)
            bias_r[mi][r] = Ball[o0 + wm * 64 + mi * 16 + quad * 4 + r];
    _Float16* Ftb = Ft + (size_t)b * NN * CKK;
    _Float16* Gtb = Gt + (size_t)b * NN * CKK;
    _Float16* Hxb = Hx + (size_t)b * CC * N;
    #pragma unroll
    for (int mi = 0; mi < 4; mi++)
        #pragma unroll
        for (int ni = 0; ni < 4; ni++) {
            int o = o0 + wm * 64 + mi * 16 + quad * 4;
            int n = n0 + wn * 64 + ni * 16 + lrow;
            f16x4 v;
            #pragma unroll
            for (int r = 0; r < 4; r++) v[r] = (_Float16)(acc[mi][ni][r] + bias_r[mi][r]);
            if (o < 64)       *(f16x4*)(Ftb + (size_t)n * CKK + o) = v;
            else if (o < 128) *(f16x4*)(Gtb + (size_t)n * CKK + (o - 64)) = v;
            else {
                #pragma unroll
                for (int r = 0; r < 4; r++)
                    Hxb[(size_t)(o - 128 + r) * N + n] = v[r];
            }
        }
}

// ---------------------------------------------------------------------------
// K2: fused flash attention, lane-local softmax + LDS-staged operands.
// Block: 128 i x 128 c, 512 threads (8 waves), grid 512 (XCD-swizzled),
// LDS 80 KB -> 2 blocks/CU.
// Wave w owns i-slice [16w,16w+16) in BOTH phases.
//   S^T = mfma(Gt_frag from BsG LDS, Ft_frag register): col i = lane&15 is
//   thread-local -> m,l in REGISTERS (4 shfl_xor total). No Mred/stats.
//   P' exchange via WAVE-PRIVATE Pst (4 KB/wave): writer and PV reader of
//   P'[i][*] are the same wave -> no barrier, packed b64 writes (thread owns
//   4 consecutive j in S^T layout), b128 reads, chunk^(i&7) swizzle.
// Barriers: 3/jt. alpha = vmcnt(0)+barrier (staged tiles landed);
//   beta = syncthreads after S-reads -> restage BsG (flies under sm+PV);
//   gamma = barrier after PV -> restage Ah (covered by co-resident block).
// ---------------------------------------------------------------------------
#define SM_AH    0         // 32768: 4 chunks [128c][32j] swizzled
#define SM_BSG   32768     // 16384: 2 chunks [128j][32k] swizzled
#define SM_PST   49152     // 32768: 8 waves x [16 i][128 j] f16, chunk^(i&7)
#define SM_TOTAL 81920

__launch_bounds__(512, 4)
__global__ void attn_fused(const _Float16* __restrict__ Ft, const _Float16* __restrict__ Gt,
                           const _Float16* __restrict__ Hx, const float* __restrict__ x,
                           const float* __restrict__ gamma, float* __restrict__ out) {
    const int N = NN;
    extern __shared__ char smem[];
    _Float16* AhL = (_Float16*)(smem + SM_AH);
    _Float16* BsG = (_Float16*)(smem + SM_BSG);
    _Float16* Pw  = (_Float16*)(smem + SM_PST);   // + w*2048 per wave

    // XCD-aware decomposition: each XCD gets 64 contiguous logical blocks
    // = all 32 i-tiles of 2 (c,b) slices (Gt/Hx L2 locality).
    int h = blockIdx.x;
    int l = (h & 7) * 64 + (h >> 3);
    int bx = l & 31;
    int by = (l >> 5) & 3;
    int b  = l >> 7;
    const int i0 = bx * 128;
    const int c0 = by * 128;

    const int tid = threadIdx.x;
    const int lane = tid & 63, w = tid >> 6;
    const int lrow = lane & 15, quad = lane >> 4;

    const _Float16* Ftb = Ft + ((size_t)b * N + i0 + w * 16) * CKK;
    const _Float16* Gtb = Gt + (size_t)b * N * CKK;
    const _Float16* Hxb = Hx + ((size_t)b * CC + c0) * N;
    _Float16* Pst = Pw + w * 2048;   // [16 i][128 j]
    const int pbase = lrow * 128;    // row i-local = lrow
    const int psw = lrow & 7;        // chunk swizzle key

    // prologue: stage Ah(0) + BsG(0); Ft frags to registers
    #pragma unroll
    for (int kk = 0; kk < 4; kk++)
        stage_swz(Hxb + kk * 32, N, AhL + kk * 4096, tid);
    stage_swz(Gtb,      CKK, BsG,        tid);
    stage_swz(Gtb + 32, CKK, BsG + 4096, tid);
    f16x8 ftf[2];
    #pragma unroll
    for (int ks = 0; ks < 2; ks++)
        ftf[ks] = *(const f16x8*)(Ftb + (size_t)lrow * CKK + ks * 32 + quad * 8);
    __syncthreads();

    f32x4 acc[8] = {};
    float m_run = -1e30f, l_run = 0.0f;

    #pragma unroll 1
    for (int jt = 0; jt < NT; jt++) {
        // ---- alpha: staged Ah(jt)+BsG(jt) landed in all waves ----
        asm volatile("s_waitcnt vmcnt(0)\n\ts_barrier" ::: "memory");

        // ---- S^T = Gt . Ft^T : sacc[jf] reg r = S[i=lrow-col][j=jf*16+quad*4+r] ----
        f32x4 sacc[8] = {};
        #pragma unroll
        for (int ks = 0; ks < 2; ks++)
            #pragma unroll
            for (int jf = 0; jf < 8; jf++) {
                f16x8 ga = rd_swz(BsG + ks * 4096, jf * 16 + lrow, quad);
                sacc[jf] = __builtin_amdgcn_mfma_f32_16x16x32_f16(ga, ftf[ks], sacc[jf], 0, 0, 0);
            }
        // ---- beta: S-reads done everywhere -> restage BsG with Gt(jt+1) ----
        __syncthreads();
        {
            const _Float16* Gn = Gtb + (size_t)((jt + 1) & (NT - 1)) * 128 * CKK;
            stage_swz(Gn,      CKK, BsG,        tid);
            stage_swz(Gn + 32, CKK, BsG + 4096, tid);
        }

        // ---- lane-local online softmax (thread owns column i) ----
        float m0 = fmaxf(fmaxf(sacc[0][0], sacc[0][1]), fmaxf(sacc[0][2], sacc[0][3]));
        #pragma unroll
        for (int jf = 1; jf < 8; jf++)
            m0 = fmaxf(m0, fmaxf(fmaxf(sacc[jf][0], sacc[jf][1]),
                                 fmaxf(sacc[jf][2], sacc[jf][3])));
        m0 = fmaxf(m0, __shfl_xor(m0, 16));
        const float mt = fmaxf(m0, __shfl_xor(m0, 32));
        const float mo = m_run;
        const float mn = fmaxf(mo, mt);
        const float sc = (mn > mo) ? __expf(mo - mn) : 1.0f;
        m_run = mn;
        if (__any(mn > mo)) {
            #pragma unroll
            for (int cf = 0; cf < 8; cf++)
                #pragma unroll
                for (int r = 0; r < 4; r++)
                    acc[cf][r] *= sc;
        }
        // P' = exp(s - m): thread owns 4 CONSECUTIVE j per jf -> packed b64
        float ls = 0.0f;
        #pragma unroll
        for (int jf = 0; jf < 8; jf++) {
            float e0 = __expf(sacc[jf][0] - mn);
            float e1 = __expf(sacc[jf][1] - mn);
            float e2 = __expf(sacc[jf][2] - mn);
            float e3 = __expf(sacc[jf][3] - mn);
            ls += (e0 + e1) + (e2 + e3);
            f16x4 pv;
            pv[0] = (_Float16)e0; pv[1] = (_Float16)e1;
            pv[2] = (_Float16)e2; pv[3] = (_Float16)e3;
            // j = jf*16 + quad*4 -> 16B chunk c = jf*2 + (quad>>1), 8B half = quad&1
            int ch = (jf * 2 + (quad >> 1)) ^ psw;
            *(f16x4*)(Pst + pbase + ch * 8 + (quad & 1) * 4) = pv;
        }
        ls += __shfl_xor(ls, 16);
        ls += __shfl_xor(ls, 32);
        l_run = l_run * sc + ls;

        // ---- PV: O[c][i] += Hx[c][j] * P'[i][j]; Pst exchange is wave-local ----
        #pragma unroll
        for (int kk = 0; kk < 4; kk++) {
            int ch = (kk * 4 + quad) ^ psw;
            f16x8 bb = *(const f16x8*)(Pst + pbase + ch * 8);
            #pragma unroll
            for (int cf = 0; cf < 8; cf++) {
                f16x8 av = rd_swz(AhL + kk * 4096, cf * 16 + lrow, quad);
                acc[cf] = __builtin_amdgcn_mfma_f32_16x16x32_f16(av, bb, acc[cf], 0, 0, 0);
            }
        }
        // ---- gamma: PV reads done -> restage Ah with Hx(jt+1) ----
        asm volatile("s_barrier" ::: "memory");
        {
            const _Float16* Hn = Hxb + (size_t)((jt + 1) & (NT - 1)) * 128;
            #pragma unroll
            for (int kk = 0; kk < 4; kk++)
                stage_swz(Hn + kk * 32, N, AhL + kk * 4096, tid);
        }
    }

    // ---- epilogue: out = gamma * (O / l) + x ----
    const float gv = gamma[0];
    const float li = 1.0f / l_run;
    const float* xb = x + (size_t)b * CC * N;
    float* ob = out + (size_t)b * CC * N;
    const int iG = i0 + w * 16 + lrow;
    #pragma unroll
    for (int cf = 0; cf < 8; cf++)
        #pragma unroll
        for (int r = 0; r < 4; r++) {
            int c = c0 + cf * 16 + quad * 4 + r;
            ob[(size_t)c * N + iG] = gv * (acc[cf][r] * li) + xb[(size_t)c * N + iG];
        }
}

extern "C" void kernel_launch(void* const* d_in, const int* in_sizes, int n_in,
                              void* d_out, int out_size, void* d_ws, size_t ws_size,
                              hipStream_t stream) {
    const float* x     = (const float*)d_in[0];
    const float* Wf    = (const float*)d_in[1];
    const float* bf    = (const float*)d_in[2];
    const float* Wg    = (const float*)d_in[3];
    const float* bg    = (const float*)d_in[4];
    const float* Wh    = (const float*)d_in[5];
    const float* bh    = (const float*)d_in[6];
    const float* gamma = (const float*)d_in[7];
    float* out = (float*)d_out;

    // Workspace layout (bytes):
    //   Wall [640][512] f16    @ 0        (640 KiB)
    //   Ball [640]      fp32   @ 768 KiB
    //   Ft   [B][N][64] f16    @ 1 MiB    (2 MiB)
    //   Gt   [B][N][64] f16    @ 3 MiB    (2 MiB)
    //   Hx   [B][C][N]  f16    @ 5 MiB    (16 MiB)
    //   xT   [B][N][C]  f16    @ 21 MiB   (17 MiB)
    char* wsb = (char*)d_ws;
    _Float16* Wall = (_Float16*)wsb;
    float*    Ball = (float*)(wsb + ((size_t)768 << 10));
    _Float16* Ft = (_Float16*)(wsb + ((size_t)1 << 20));
    _Float16* Gt = (_Float16*)(wsb + ((size_t)3 << 20));
    _Float16* Hx = (_Float16*)(wsb + ((size_t)5 << 20));
    _Float16* xT = (_Float16*)(wsb + ((size_t)21 << 20));

    static const bool attn_attr_once = [] {
        hipFuncSetAttribute((const void*)attn_fused,
                            hipFuncAttributeMaxDynamicSharedMemorySize, SM_TOTAL);
        return true;
    }();
    (void)attn_attr_once;

    prep<<<dim3(2048 + 640), dim3(256), 0, stream>>>(
        x, xT, Wf, bf, Wg, bg, Wh, bh, Wall, Ball);
    proj_mfma<<<dim3(NN / 128, 5, NB), dim3(256), 0, stream>>>(xT, Wall, Ball, Ft, Gt, Hx);
    attn_fused<<<dim3(512), dim3(512), SM_TOTAL, stream>>>(
        Ft, Gt, Hx, x, gamma, out);
}

// Round 8
// 247.721 us; speedup vs baseline: 1.6813x; 1.0293x over previous
//
#include <hip/hip_runtime.h>
#include <hip/hip_bf16.h>

// Problem constants: B=4, C=512, H=W=64 -> N=4096, CK=64
#define NB 4
#define CC 512
#define NN 4096
#define CKK 64
#define NT 32   // NN/128 j-tiles

typedef _Float16 f16x4 __attribute__((ext_vector_type(4)));
typedef _Float16 f16x8 __attribute__((ext_vector_type(8)));
typedef float    f32x4 __attribute__((ext_vector_type(4)));

// ---------------------------------------------------------------------------
// async global->LDS, 16 B per lane. LDS dest is wave-uniform base + lane*16.
// ---------------------------------------------------------------------------
__device__ __forceinline__ void g2l16(const _Float16* g, _Float16* l) {
    __builtin_amdgcn_global_load_lds(
        (const __attribute__((address_space(1))) void*)g,
        (__attribute__((address_space(3))) void*)l, 16, 0, 0);
}

// Stage a 128-row x 32-col f16 tile (row stride ldg) into LDS [128][32],
// 256 threads (4 waves). Linear layout (used by proj).
__device__ __forceinline__ void stage_tile(const _Float16* __restrict__ g, int ldg,
                                           _Float16* lds, int lane, int wave) {
    #pragma unroll
    for (int r = 0; r < 2; r++) {
        int q = r * 4 + wave;
        int row = q * 16 + (lane >> 2);
        int col = (lane & 3) * 8;
        g2l16(g + (size_t)row * ldg + col, lds + q * 512 + lane * 8);
    }
}

// Stage a 128x32 f16 tile with 512 threads, ONE g2l16 per thread.
// LDS dest linear (required by global_load_lds); the GLOBAL source chunk is
// pre-permuted by (row>>1)&3 -> stored layout is XOR-swizzled; rd_swz reads.
__device__ __forceinline__ void stage_swz(const _Float16* __restrict__ g, int ldg,
                                          _Float16* lds, int tid) {
    int row = tid >> 2;
    int scq = (tid & 3) ^ ((row >> 1) & 3);
    g2l16(g + (size_t)row * ldg + scq * 8, lds + tid * 8);
}

__device__ __forceinline__ f16x8 rd_swz(const _Float16* lds, int row, int quad) {
    int q = quad ^ ((row >> 1) & 3);
    return *(const f16x8*)(lds + row * 32 + q * 8);
}

// ---------------------------------------------------------------------------
// K0 "prep": blocks 0..2047 transpose x (fp32 [B][C][N]) -> xT (f16 [B][N][C]);
// blocks 2048..2687 pack Wf/Wg/Wh -> Wall[640][512] f16 + Ball[640] fp32.
// ---------------------------------------------------------------------------
__launch_bounds__(256)
__global__ void prep(const float* __restrict__ x, _Float16* __restrict__ xT,
                     const float* __restrict__ Wf, const float* __restrict__ bf_,
                     const float* __restrict__ Wg, const float* __restrict__ bg_,
                     const float* __restrict__ Wh, const float* __restrict__ bh_,
                     _Float16* __restrict__ Wall, float* __restrict__ Ball) {
    const int N = NN, C = CC;
    int bid = blockIdx.x;
    int t = threadIdx.x;
    if (bid < 2048) {
        int n0 = (bid & 63) << 6;
        int c0 = ((bid >> 6) & 7) << 6;
        int b  = bid >> 9;
        __shared__ float T[64][65];
        const float* xb = x + (size_t)b * C * N;
        #pragma unroll
        for (int r = 0; r < 4; r++) {
            int c = (t >> 4) + 16 * r;
            int n4 = (t & 15) * 4;
            float4 v = *(const float4*)(xb + (size_t)(c0 + c) * N + n0 + n4);
            T[n4 + 0][c] = v.x; T[n4 + 1][c] = v.y; T[n4 + 2][c] = v.z; T[n4 + 3][c] = v.w;
        }
        __syncthreads();
        int n = t >> 2, cb = (t & 3) * 16;
        f16x8 h0, h1;
        #pragma unroll
        for (int i = 0; i < 8; i++) { h0[i] = (_Float16)T[n][cb + i]; h1[i] = (_Float16)T[n][cb + 8 + i]; }
        _Float16* dst = xT + (size_t)b * N * C + (size_t)(n0 + n) * C + c0 + cb;
        *(f16x8*)dst = h0;
        *(f16x8*)(dst + 8) = h1;
    } else {
        int o = bid - 2048;  // 0..639
        const float* src;
        if (o < 64)       src = Wf + (size_t)o * C;
        else if (o < 128) src = Wg + (size_t)(o - 64) * C;
        else              src = Wh + (size_t)(o - 128) * C;
        Wall[(size_t)o * C + t]       = (_Float16)src[t];
        Wall[(size_t)o * C + 256 + t] = (_Float16)src[256 + t];
        if (t == 0)
            Ball[o] = (o < 64) ? bf_[o] : (o < 128 ? bg_[o - 64] : bh_[o - 128]);
    }
}

// ---------------------------------------------------------------------------
// K1: projections, NT MFMA GEMM. Y[o][n] = sum_c Wall[o][c]*xT[n][c] + Ball[o]
// ---------------------------------------------------------------------------
__launch_bounds__(256)
__global__ void proj_mfma(const _Float16* __restrict__ xT, const _Float16* __restrict__ Wall,
                          const float* __restrict__ Ball,
                          _Float16* __restrict__ Ft, _Float16* __restrict__ Gt,
                          _Float16* __restrict__ Hx) {
    const int N = NN, C = CC;
    int n0 = blockIdx.x * 128;
    int o0 = blockIdx.y * 128;
    int b  = blockIdx.z;
    const _Float16* Arow = Wall + (size_t)o0 * C;
    const _Float16* Brow = xT + (size_t)b * N * C + (size_t)n0 * C;
    __shared__ _Float16 As[128 * 32];
    __shared__ _Float16 Bs[128 * 32];
    int tid = threadIdx.x, lane = tid & 63, wave = tid >> 6;
    int wm = wave & 1, wn = wave >> 1, lrow = lane & 15, quad = lane >> 4;
    f32x4 acc[4][4] = {};
    for (int kc = 0; kc < C; kc += 32) {
        __syncthreads();
        stage_tile(Arow + kc, C, As, lane, wave);
        stage_tile(Brow + kc, C, Bs, lane, wave);
        __syncthreads();
        f16x8 af[4], bf[4];
        #pragma unroll
        for (int mi = 0; mi < 4; mi++)
            af[mi] = *(const f16x8*)(As + (wm * 64 + mi * 16 + lrow) * 32 + quad * 8);
        #pragma unroll
        for (int ni = 0; ni < 4; ni++)
            bf[ni] = *(const f16x8*)(Bs + (wn * 64 + ni * 16 + lrow) * 32 + quad * 8);
        #pragma unroll
        for (int mi = 0; mi < 4; mi++)
            #pragma unroll
            for (int ni = 0; ni < 4; ni++)
                acc[mi][ni] = __builtin_amdgcn_mfma_f32_16x16x32_f16(af[mi], bf[ni], acc[mi][ni], 0, 0, 0);
    }
    float bias_r[4][4];
    #pragma unroll
    for (int mi = 0; mi < 4; mi++)
        #pragma unroll
        for (int r = 0; r < 4; r++)
            bias_r[mi][r] = Ball[o0 + wm * 64 + mi * 16 + quad * 4 + r];
    _Float16* Ftb = Ft + (size_t)b * NN * CKK;
    _Float16* Gtb = Gt + (size_t)b * NN * CKK;
    _Float16* Hxb = Hx + (size_t)b * CC * N;
    #pragma unroll
    for (int mi = 0; mi < 4; mi++)
        #pragma unroll
        for (int ni = 0; ni < 4; ni++) {
            int o = o0 + wm * 64 + mi * 16 + quad * 4;
            int n = n0 + wn * 64 + ni * 16 + lrow;
            f16x4 v;
            #pragma unroll
            for (int r = 0; r < 4; r++) v[r] = (_Float16)(acc[mi][ni][r] + bias_r[mi][r]);
            if (o < 64)       *(f16x4*)(Ftb + (size_t)n * CKK + o) = v;
            else if (o < 128) *(f16x4*)(Gtb + (size_t)n * CKK + (o - 64)) = v;
            else {
                #pragma unroll
                for (int r = 0; r < 4; r++)
                    Hxb[(size_t)(o - 128 + r) * N + n] = v[r];
            }
        }
}

// ---------------------------------------------------------------------------
// K2: fused flash attention, lane-local softmax + counted-vmcnt phases.
// Block: 128 i x 128 c, 512 threads (8 waves), grid 512 (XCD-swizzled),
// LDS 80 KB -> 2 blocks/CU.
// Per j-tile (steady state; BsG = 2 loads/thread, Ah = 4 loads/thread):
//   alpha  vmcnt(4)+bar : BsG(jt) landed, 4 Ah(jt) STAY IN FLIGHT
//   S^T MFMA (reads BsG only)
//   beta   lgkmcnt(0)+bar -> restage BsG(jt+1)    [raw: no vmcnt drain!]
//   softmax (defer-max THR=8; m,l in registers; Pst wave-private writes)
//   prePV  vmcnt(2)+bar : Ah(jt) landed (covered by S+softmax), BsG(jt+1) flies
//   PV MFMA (reads Ah + Pst)
//   gamma  lgkmcnt(0)+bar -> restage Ah(jt+1)
// vmcnt age-order verified incl. iter 0 with compiler-scheduled ftf loads:
// waits can only over-retire, never under-retire the required group.
// ---------------------------------------------------------------------------
#define SM_AH    0         // 32768: 4 chunks [128c][32j] swizzled
#define SM_BSG   32768     // 16384: 2 chunks [128j][32k] swizzled
#define SM_PST   49152     // 32768: 8 waves x [16 i][128 j] f16, chunk^(i&7)
#define SM_TOTAL 81920

__launch_bounds__(512, 4)
__global__ void attn_fused(const _Float16* __restrict__ Ft, const _Float16* __restrict__ Gt,
                           const _Float16* __restrict__ Hx, const float* __restrict__ x,
                           const float* __restrict__ gamma, float* __restrict__ out) {
    const int N = NN;
    extern __shared__ char smem[];
    _Float16* AhL = (_Float16*)(smem + SM_AH);
    _Float16* BsG = (_Float16*)(smem + SM_BSG);
    _Float16* Pw  = (_Float16*)(smem + SM_PST);   // + w*2048 per wave

    // XCD-aware decomposition: each XCD gets 64 contiguous logical blocks
    // = all 32 i-tiles of 2 (c,b) slices (Gt/Hx L2 locality).
    int h = blockIdx.x;
    int l = (h & 7) * 64 + (h >> 3);
    int bx = l & 31;
    int by = (l >> 5) & 3;
    int b  = l >> 7;
    const int i0 = bx * 128;
    const int c0 = by * 128;

    const int tid = threadIdx.x;
    const int lane = tid & 63, w = tid >> 6;
    const int lrow = lane & 15, quad = lane >> 4;

    const _Float16* Ftb = Ft + ((size_t)b * N + i0 + w * 16) * CKK;
    const _Float16* Gtb = Gt + (size_t)b * N * CKK;
    const _Float16* Hxb = Hx + ((size_t)b * CC + c0) * N;
    _Float16* Pst = Pw + w * 2048;   // [16 i][128 j]
    const int pbase = lrow * 128;    // row i-local = lrow
    const int psw = lrow & 7;        // chunk swizzle key

    // prologue: issue BsG(0) FIRST (older), then Ah(0) -- matches steady-state
    // age order so alpha's vmcnt(4) retires exactly BsG.
    stage_swz(Gtb,      CKK, BsG,        tid);
    stage_swz(Gtb + 32, CKK, BsG + 4096, tid);
    #pragma unroll
    for (int kk = 0; kk < 4; kk++)
        stage_swz(Hxb + kk * 32, N, AhL + kk * 4096, tid);
    f16x8 ftf[2];
    #pragma unroll
    for (int ks = 0; ks < 2; ks++)
        ftf[ks] = *(const f16x8*)(Ftb + (size_t)lrow * CKK + ks * 32 + quad * 8);

    f32x4 acc[8] = {};
    float m_run = -1e30f, l_run = 0.0f;

    #pragma unroll 1
    for (int jt = 0; jt < NT; jt++) {
        // ---- alpha: BsG(jt) landed; Ah(jt) still in flight ----
        asm volatile("s_waitcnt vmcnt(4)\n\ts_barrier" ::: "memory");

        // ---- S^T = Gt . Ft^T : sacc[jf] reg r = S[i=lrow-col][j=jf*16+quad*4+r] ----
        f32x4 sacc[8] = {};
        #pragma unroll
        for (int ks = 0; ks < 2; ks++)
            #pragma unroll
            for (int jf = 0; jf < 8; jf++) {
                f16x8 ga = rd_swz(BsG + ks * 4096, jf * 16 + lrow, quad);
                sacc[jf] = __builtin_amdgcn_mfma_f32_16x16x32_f16(ga, ftf[ks], sacc[jf], 0, 0, 0);
            }
        // ---- beta: S-reads done everywhere -> restage BsG(jt+1) ----
        // raw lgkm-only barrier: __syncthreads would drain vmcnt and kill the
        // in-flight Ah prefetch.
        asm volatile("s_waitcnt lgkmcnt(0)\n\ts_barrier" ::: "memory");
        {
            const _Float16* Gn = Gtb + (size_t)((jt + 1) & (NT - 1)) * 128 * CKK;
            stage_swz(Gn,      CKK, BsG,        tid);
            stage_swz(Gn + 32, CKK, BsG + 4096, tid);
        }

        // ---- lane-local online softmax (thread owns column i) ----
        float m0 = fmaxf(fmaxf(sacc[0][0], sacc[0][1]), fmaxf(sacc[0][2], sacc[0][3]));
        #pragma unroll
        for (int jf = 1; jf < 8; jf++)
            m0 = fmaxf(m0, fmaxf(fmaxf(sacc[jf][0], sacc[jf][1]),
                                 fmaxf(sacc[jf][2], sacc[jf][3])));
        m0 = fmaxf(m0, __shfl_xor(m0, 16));
        const float mt = fmaxf(m0, __shfl_xor(m0, 32));
        const float mo = m_run;
        float mn, sc;
        // defer-max (T13): only rescale when some lane's tile max exceeds its
        // running max by >8. Otherwise keep stale m; P' bounded by e^8 (f16 ok),
        // l_run <= 4096*e^8 ~ 1.2e7 (f32 ok). Math exact either way.
        if (__any(mt > mo + 8.0f)) {
            mn = fmaxf(mo, mt);
            sc = __expf(mo - mn);   // first tile: exp(-huge) = 0
            m_run = mn;
            #pragma unroll
            for (int cf = 0; cf < 8; cf++)
                #pragma unroll
                for (int r = 0; r < 4; r++)
                    acc[cf][r] *= sc;
        } else {
            mn = mo;
            sc = 1.0f;
        }
        // P' = exp(s - m): thread owns 4 CONSECUTIVE j per jf -> packed b64
        float ls = 0.0f;
        #pragma unroll
        for (int jf = 0; jf < 8; jf++) {
            float e0 = __expf(sacc[jf][0] - mn);
            float e1 = __expf(sacc[jf][1] - mn);
            float e2 = __expf(sacc[jf][2] - mn);
            float e3 = __expf(sacc[jf][3] - mn);
            ls += (e0 + e1) + (e2 + e3);
            f16x4 pv;
            pv[0] = (_Float16)e0; pv[1] = (_Float16)e1;
            pv[2] = (_Float16)e2; pv[3] = (_Float16)e3;
            // j = jf*16 + quad*4 -> 16B chunk c = jf*2 + (quad>>1), 8B half = quad&1
            int ch = (jf * 2 + (quad >> 1)) ^ psw;
            *(f16x4*)(Pst + pbase + ch * 8 + (quad & 1) * 4) = pv;
        }
        ls += __shfl_xor(ls, 16);
        ls += __shfl_xor(ls, 32);
        l_run = l_run * sc + ls;

        // ---- prePV: Ah(jt) landed (latency hidden under S+softmax);
        //      the 2 BsG(jt+1) loads stay in flight ----
        asm volatile("s_waitcnt vmcnt(2)\n\ts_barrier" ::: "memory");

        // ---- PV: O[c][i] += Hx[c][j] * P'[i][j]; Pst exchange is wave-local ----
        #pragma unroll
        for (int kk = 0; kk < 4; kk++) {
            int ch = (kk * 4 + quad) ^ psw;
            f16x8 bb = *(const f16x8*)(Pst + pbase + ch * 8);
            #pragma unroll
            for (int cf = 0; cf < 8; cf++) {
                f16x8 av = rd_swz(AhL + kk * 4096, cf * 16 + lrow, quad);
                acc[cf] = __builtin_amdgcn_mfma_f32_16x16x32_f16(av, bb, acc[cf], 0, 0, 0);
            }
        }
        // ---- gamma: PV reads done -> restage Ah(jt+1) ----
        asm volatile("s_waitcnt lgkmcnt(0)\n\ts_barrier" ::: "memory");
        {
            const _Float16* Hn = Hxb + (size_t)((jt + 1) & (NT - 1)) * 128;
            #pragma unroll
            for (int kk = 0; kk < 4; kk++)
                stage_swz(Hn + kk * 32, N, AhL + kk * 4096, tid);
        }
    }

    // ---- epilogue: out = gamma * (O / l) + x ----
    const float gv = gamma[0];
    const float li = 1.0f / l_run;
    const float* xb = x + (size_t)b * CC * N;
    float* ob = out + (size_t)b * CC * N;
    const int iG = i0 + w * 16 + lrow;
    #pragma unroll
    for (int cf = 0; cf < 8; cf++)
        #pragma unroll
        for (int r = 0; r < 4; r++) {
            int c = c0 + cf * 16 + quad * 4 + r;
            ob[(size_t)c * N + iG] = gv * (acc[cf][r] * li) + xb[(size_t)c * N + iG];
        }
}

extern "C" void kernel_launch(void* const* d_in, const int* in_sizes, int n_in,
                              void* d_out, int out_size, void* d_ws, size_t ws_size,
                              hipStream_t stream) {
    const float* x     = (const float*)d_in[0];
    const float* Wf    = (const float*)d_in[1];
    const float* bf    = (const float*)d_in[2];
    const float* Wg    = (const float*)d_in[3];
    const float* bg    = (const float*)d_in[4];
    const float* Wh    = (const float*)d_in[5];
    const float* bh    = (const float*)d_in[6];
    const float* gamma = (const float*)d_in[7];
    float* out = (float*)d_out;

    // Workspace layout (bytes):
    //   Wall [640][512] f16    @ 0        (640 KiB)
    //   Ball [640]      fp32   @ 768 KiB
    //   Ft   [B][N][64] f16    @ 1 MiB    (2 MiB)
    //   Gt   [B][N][64] f16    @ 3 MiB    (2 MiB)
    //   Hx   [B][C][N]  f16    @ 5 MiB    (16 MiB)
    //   xT   [B][N][C]  f16    @ 21 MiB   (17 MiB)
    char* wsb = (char*)d_ws;
    _Float16* Wall = (_Float16*)wsb;
    float*    Ball = (float*)(wsb + ((size_t)768 << 10));
    _Float16* Ft = (_Float16*)(wsb + ((size_t)1 << 20));
    _Float16* Gt = (_Float16*)(wsb + ((size_t)3 << 20));
    _Float16* Hx = (_Float16*)(wsb + ((size_t)5 << 20));
    _Float16* xT = (_Float16*)(wsb + ((size_t)21 << 20));

    static const bool attn_attr_once = [] {
        hipFuncSetAttribute((const void*)attn_fused,
                            hipFuncAttributeMaxDynamicSharedMemorySize, SM_TOTAL);
        return true;
    }();
    (void)attn_attr_once;

    prep<<<dim3(2048 + 640), dim3(256), 0, stream>>>(
        x, xT, Wf, bf, Wg, bg, Wh, bh, Wall, Ball);
    proj_mfma<<<dim3(NN / 128, 5, NB), dim3(256), 0, stream>>>(xT, Wall, Ball, Ft, Gt, Hx);
    attn_fused<<<dim3(512), dim3(512), SM_TOTAL, stream>>>(
        Ft, Gt, Hx, x, gamma, out);
}